// Round 8
// baseline (265.723 us; speedup 1.0000x reference)
//
#include <hip/hip_runtime.h>

#define BB 16
#define SS 512
#define KIN 512
#define H 256

typedef float v2f __attribute__((ext_vector_type(2)));

constexpr float DECAY = 0.951229424500714f;    // exp(-1/20), both tau=20
constexpr float OMD   = 0.048770575499286f;    // 1 - exp(-1/20)
constexpr float LR    = 0.01f;

__device__ __forceinline__ float fast_tanh(float x) {
    float e = __expf(2.f * x);
    return 1.f - __fdividef(2.f, e + 1.f);
}

__device__ __forceinline__ v2f pk_mul(v2f a, v2f b) {
    v2f d; asm("v_pk_mul_f32 %0, %1, %2" : "=v"(d) : "v"(a), "v"(b)); return d;
}
__device__ __forceinline__ v2f pk_fma(v2f a, v2f b, v2f c) {
    v2f d; asm("v_pk_fma_f32 %0, %1, %2, %3" : "=v"(d) : "v"(a), "v"(b), "v"(c)); return d;
}

// Half-wave (32-lane) sums via DPP prefix + row_bcast15; lane31/63 hold sums.
__device__ __forceinline__ void half_sum32(float x, float& s_lo, float& s_hi) {
    int t;
    t = __builtin_amdgcn_update_dpp(0, __float_as_int(x), 0x111, 0xf, 0xf, false);
    x += __int_as_float(t);
    t = __builtin_amdgcn_update_dpp(0, __float_as_int(x), 0x112, 0xf, 0xf, false);
    x += __int_as_float(t);
    t = __builtin_amdgcn_update_dpp(0, __float_as_int(x), 0x114, 0xf, 0xf, false);
    x += __int_as_float(t);
    t = __builtin_amdgcn_update_dpp(0, __float_as_int(x), 0x118, 0xf, 0xf, false);
    x += __int_as_float(t);
    t = __builtin_amdgcn_update_dpp(0, __float_as_int(x), 0x142, 0xa, 0xf, false);
    x += __int_as_float(t);
    s_lo = __int_as_float(__builtin_amdgcn_readlane(__float_as_int(x), 31));
    s_hi = __int_as_float(__builtin_amdgcn_readlane(__float_as_int(x), 63));
}

// i = x @ W^T. ik half (n<256) -> ik_out[b*512+s][256]; iv half -> iv_t[b][row][s].
__global__ __launch_bounds__(256) void gemm_xwT(const float* __restrict__ X,
                                                const float* __restrict__ W,
                                                float* __restrict__ ik_out,
                                                float* __restrict__ iv_t) {
    __shared__ float As[16][68];
    __shared__ float Bs[16][68];
    const int m0 = blockIdx.y * 64;
    const int n0 = blockIdx.x * 64;
    const int tid = threadIdx.x;
    const int r  = tid >> 2;
    const int cg = tid & 3;
    const int tx = tid & 15;
    const int ty = tid >> 4;
    float acc[4][4] = {};
    for (int k0 = 0; k0 < KIN; k0 += 16) {
        float4 av = *(const float4*)&X[(size_t)(m0 + r) * KIN + k0 + cg * 4];
        float4 bv = *(const float4*)&W[(size_t)(n0 + r) * KIN + k0 + cg * 4];
        __syncthreads();
        As[cg*4+0][r] = av.x; As[cg*4+1][r] = av.y; As[cg*4+2][r] = av.z; As[cg*4+3][r] = av.w;
        Bs[cg*4+0][r] = bv.x; Bs[cg*4+1][r] = bv.y; Bs[cg*4+2][r] = bv.z; Bs[cg*4+3][r] = bv.w;
        __syncthreads();
#pragma unroll
        for (int kk = 0; kk < 16; ++kk) {
            float4 a = *(const float4*)&As[kk][ty * 4];
            float4 b = *(const float4*)&Bs[kk][tx * 4];
            float ar[4] = {a.x, a.y, a.z, a.w};
            float br[4] = {b.x, b.y, b.z, b.w};
#pragma unroll
            for (int i = 0; i < 4; ++i)
#pragma unroll
                for (int j = 0; j < 4; ++j) acc[i][j] += ar[i] * br[j];
        }
    }
    if (n0 < 256) {
#pragma unroll
        for (int i = 0; i < 4; ++i) {
            float4 o = make_float4(acc[i][0], acc[i][1], acc[i][2], acc[i][3]);
            *(float4*)&ik_out[(size_t)(m0 + ty * 4 + i) * 256 + n0 + tx * 4] = o;
        }
    } else {
        const int b  = m0 >> 9;
        const int s0 = (m0 & 511) + ty * 4;
#pragma unroll
        for (int j = 0; j < 4; ++j) {
            float4 o = make_float4(acc[0][j], acc[1][j], acc[2][j], acc[3][j]);
            *(float4*)&iv_t[((size_t)b * H + (n0 - 256 + tx * 4 + j)) * SS + s0] = o;
        }
    }
}

// Per (b, col): scan kv, write key only. 32-deep prefetch.
__global__ __launch_bounds__(64) void key_scan(const float* __restrict__ ik,
                                               float* __restrict__ keys) {
    const int idx = blockIdx.x * 64 + threadIdx.x;   // 0..4095
    const int b   = idx >> 8;
    const int col = idx & 255;
    const float* c  = ik + (size_t)b * SS * 256 + col;
    float* ko = keys + (size_t)b * SS * H + col;
    float kv = 0.f;
    constexpr int D = 32;
    float ib[D];
#pragma unroll
    for (int j = 0; j < D; ++j) ib[j] = c[(size_t)j * 256];
    for (int t = 0; t < SS; t += D) {
#pragma unroll
        for (int j = 0; j < D; ++j) {
            float v = ib[j];
            int tn = t + D + j; if (tn > SS - 1) tn = SS - 1;
            ib[j] = c[(size_t)tn * 256];
            kv = DECAY * kv + v;
            ko[(size_t)(t + j) * H] = fast_tanh(kv);
        }
    }
}

// 2 mem-rows per wave (32 lanes/row, 8 cols/lane). Keys staged cooperatively in
// LDS (16-step tiles, double-buffered, column-swizzled for conflict-free b64
// reads); global->LDS pipeline is barrier-ordered so the compiler can't sink it.
__global__ __launch_bounds__(256, 2) void value_scan(const float* __restrict__ keys,
                                                     const float* __restrict__ iv_t,
                                                     float* __restrict__ mem_out,
                                                     float* __restrict__ vals) {
    __shared__ float klds[2][16][256];   // 32 KB, col c at ((c>>1)&3)*64+(c>>3)*2+(c&1)
    const int tid  = threadIdx.x;
    const int wave = tid >> 6;
    const int lane = tid & 63;
    const int half = lane >> 5;
    const int sub  = lane & 31;
    const int b    = blockIdx.x & 15;     // XCD swizzle: batch-mates share an XCD
    const int rg   = blockIdx.x >> 4;
    const int row  = rg * 8 + wave * 2 + half;
    const int sub2 = sub * 2;
    const int lane4 = lane * 4;
    const int s2   = (lane >> 1) * 2;
    const int q2a  = (lane * 2) & 3;
    const int q2b  = (lane * 2 + 1) & 3;

    const float* kb  = keys + (size_t)b * SS * H;           // block-uniform
    const float* ivp = iv_t + ((size_t)b * H + row) * SS;   // marching
    float* vrow = vals + (size_t)b * SS * H + row;          // marching

    const v2f DEC2 = {DECAY, DECAY};
    const v2f OMD2 = {OMD, OMD};
    const v2f ONE2 = {1.f, 1.f};
    const v2f NM12 = {-1.f, -1.f};

    v2f mem2[4] = {{0.f,0.f},{0.f,0.f},{0.f,0.f},{0.f,0.f}};
    v2f ktr[4]  = {{0.f,0.f},{0.f,0.f},{0.f,0.f},{0.f,0.f}};
    float vv = 0.f, vt = 0.f, stash = 0.f;
    v2f ring[2][4];
    float4 g0, g1, g2, g3;

#define LOADG(TI) {                                                            \
        const float* gp_ = kb + (size_t)((TI) * 16 + wave * 4) * H + lane4;    \
        g0 = *(const float4*)(gp_);                                            \
        g1 = *(const float4*)(gp_ + H);                                        \
        g2 = *(const float4*)(gp_ + 2 * H);                                    \
        g3 = *(const float4*)(gp_ + 3 * H);                                    \
    }

#define STAGE(BUF) {                                                           \
        float* rb_ = &klds[BUF][wave * 4][0];                                  \
        *(v2f*)(rb_ + q2a * 64 + s2)       = v2f{g0.x, g0.y};                  \
        *(v2f*)(rb_ + q2b * 64 + s2)       = v2f{g0.z, g0.w};                  \
        *(v2f*)(rb_ + 256 + q2a * 64 + s2) = v2f{g1.x, g1.y};                  \
        *(v2f*)(rb_ + 256 + q2b * 64 + s2) = v2f{g1.z, g1.w};                  \
        *(v2f*)(rb_ + 512 + q2a * 64 + s2) = v2f{g2.x, g2.y};                  \
        *(v2f*)(rb_ + 512 + q2b * 64 + s2) = v2f{g2.z, g2.w};                  \
        *(v2f*)(rb_ + 768 + q2a * 64 + s2) = v2f{g3.x, g3.y};                  \
        *(v2f*)(rb_ + 768 + q2b * 64 + s2) = v2f{g3.z, g3.w};                  \
    }

#define RD(J, SLOT) {                                                          \
        const float* r_ = &klds[cur][J][sub2];                                 \
        ring[SLOT][0] = *(const v2f*)(r_);                                     \
        ring[SLOT][1] = *(const v2f*)(r_ + 64);                                \
        ring[SLOT][2] = *(const v2f*)(r_ + 128);                               \
        ring[SLOT][3] = *(const v2f*)(r_ + 192);                               \
    }

#define VS_STEP(J)                                                             \
    {                                                                          \
        v2f kc0 = ring[(J)&1][0], kc1 = ring[(J)&1][1],                        \
            kc2 = ring[(J)&1][2], kc3 = ring[(J)&1][3];                        \
        if ((J) < 14) RD((J) + 2, (J)&1);                                      \
        v2f p2 = pk_mul(mem2[0], kc0);                                         \
        p2 = pk_fma(mem2[1], kc1, p2);                                         \
        p2 = pk_fma(mem2[2], kc2, p2);                                         \
        p2 = pk_fma(mem2[3], kc3, p2);                                         \
        float slo, shi;                                                        \
        half_sum32(p2.x + p2.y, slo, shi);                                     \
        float ps = half ? shi : slo;                                           \
        vv = __builtin_fmaf(DECAY, vv, ivs[J]);                                \
        vv = __builtin_fmaf(0.2f, ps, vv);                                     \
        float valv = fast_tanh(vv);                                            \
        vt = __builtin_fmaf(DECAY, vt, OMD * valv);                            \
        if (sub == (J)) stash = valv;                                          \
        float c = LR * vt;                                                     \
        v2f c2 = {c, c};                                                       \
        ktr[0] = pk_fma(DEC2, ktr[0], pk_mul(OMD2, kc0));                      \
        ktr[1] = pk_fma(DEC2, ktr[1], pk_mul(OMD2, kc1));                      \
        ktr[2] = pk_fma(DEC2, ktr[2], pk_mul(OMD2, kc2));                      \
        ktr[3] = pk_fma(DEC2, ktr[3], pk_mul(OMD2, kc3));                      \
        v2f d0 = pk_fma(mem2[0], NM12, ONE2);                                  \
        v2f d1 = pk_fma(mem2[1], NM12, ONE2);                                  \
        v2f d2 = pk_fma(mem2[2], NM12, ONE2);                                  \
        v2f d3 = pk_fma(mem2[3], NM12, ONE2);                                  \
        mem2[0] = pk_fma(pk_mul(c2, ktr[0]), d0, mem2[0]);                     \
        mem2[1] = pk_fma(pk_mul(c2, ktr[1]), d1, mem2[1]);                     \
        mem2[2] = pk_fma(pk_mul(c2, ktr[2]), d2, mem2[2]);                     \
        mem2[3] = pk_fma(pk_mul(c2, ktr[3]), d3, mem2[3]);                     \
    }

    // prolog: tile0 -> LDS[0]; tile1 -> regs; iv tile0 -> regs
    LOADG(0);
    STAGE(0);
    LOADG(1);
    float4 ivA0 = *(const float4*)(ivp);
    float4 ivA1 = *(const float4*)(ivp + 4);
    float4 ivB0 = *(const float4*)(ivp + 8);
    float4 ivB1 = *(const float4*)(ivp + 12);
    ivp += 16;
    __syncthreads();

    int cur = 0;
    for (int tile = 0; tile < 32; ++tile) {
        RD(0, 0); RD(1, 1);               // reg-prefetch steps 0,1 of this tile
        STAGE(cur ^ 1);                   // write tile+1 (in g) to other buffer
        int tnext = tile + 2; if (tnext > 31) tnext = 31;
        LOADG(tnext);                     // issue tile+2 loads (16 steps ahead)
        const float* ivq = (tile < 31) ? ivp : (ivp - 16);
        float4 nA0 = *(const float4*)(ivq);
        float4 nA1 = *(const float4*)(ivq + 4);
        float4 nB0 = *(const float4*)(ivq + 8);
        float4 nB1 = *(const float4*)(ivq + 12);
        ivp += 16;
        {
            float ivs[16] = {ivA0.x, ivA0.y, ivA0.z, ivA0.w,
                             ivA1.x, ivA1.y, ivA1.z, ivA1.w,
                             ivB0.x, ivB0.y, ivB0.z, ivB0.w,
                             ivB1.x, ivB1.y, ivB1.z, ivB1.w};
            VS_STEP(0)  VS_STEP(1)  VS_STEP(2)  VS_STEP(3)
            VS_STEP(4)  VS_STEP(5)  VS_STEP(6)  VS_STEP(7)
            VS_STEP(8)  VS_STEP(9)  VS_STEP(10) VS_STEP(11)
            VS_STEP(12) VS_STEP(13) VS_STEP(14) VS_STEP(15)
        }
        if (sub < 16) vrow[(size_t)sub * H] = stash;
        vrow += 16 * H;
        ivA0 = nA0; ivA1 = nA1; ivB0 = nB0; ivB1 = nB1;
        __syncthreads();
        cur ^= 1;
    }
#undef VS_STEP
#undef RD
#undef STAGE
#undef LOADG

    float* mo = &mem_out[((size_t)b * H + row) * H + sub * 8];
    *(float4*)&mo[0] = make_float4(mem2[0].x, mem2[0].y, mem2[1].x, mem2[1].y);
    *(float4*)&mo[4] = make_float4(mem2[2].x, mem2[2].y, mem2[3].x, mem2[3].y);
}

extern "C" void kernel_launch(void* const* d_in, const int* in_sizes, int n_in,
                              void* d_out, int out_size, void* d_ws, size_t ws_size,
                              hipStream_t stream) {
    const float* x = (const float*)d_in[0];   // [B, S, IN] f32
    const float* W = (const float*)d_in[1];   // [2H, IN] f32
    float* out = (float*)d_out;
    float* mem_out = out;                               // [B, H, H]
    float* keys = out + (size_t)BB * H * H;             // [B, S, H]
    float* vals = keys + (size_t)BB * SS * H;           // [B, S, H]
    float* ik   = (float*)d_ws;                         // [B*S, 256]  8 MB
    float* iv_t = ik + (size_t)BB * SS * 256;           // [B, H, S]   8 MB

    dim3 gb(8, 128);  // N/64, M/64
    gemm_xwT<<<gb, 256, 0, stream>>>(x, W, ik, iv_t);
    key_scan<<<64, 64, 0, stream>>>(ik, keys);
    value_scan<<<512, 256, 0, stream>>>(keys, iv_t, mem_out, vals);
}